// Round 14
// baseline (178.332 us; speedup 1.0000x reference)
//
#include <hip/hip_runtime.h>
#include <stdint.h>

// TriXTile: out = (relu((x @ sign(up_w)^T) * up_scale) @ sign(down_w)^T) * down_scale * out_scale
// Round 14: r13 conveyor + SWAPPED MFMA OPERANDS in GEMM1. i8 MFMA A/B frag
// layouts are symmetric, so mfma(b,a) gives the transposed C tile: lane holds
// 4 CONSECUTIVE output columns -> epilogue packs 4 quantized bytes into one
// u32 store (16 stores/thread vs 64 byte-stores; VMEM queue 76->32, under the
// 63 limit; stores clear the vmcnt ledger a full tile early). Output
// bit-identical (exact i32 accum, same per-element float epilogue).
// GEMM2 and prep byte-identical to r13.

#define M_TOK 4096
#define DM 2048
#define DH 8192

typedef __attribute__((ext_vector_type(4))) int i32x4;

#define GLD16(g, l)                                                     \
  __builtin_amdgcn_global_load_lds(                                     \
      (const __attribute__((address_space(1))) void*)(g),               \
      (__attribute__((address_space(3))) void*)(l), 16, 0, 0)

// ---- merged prepass (r9 verbatim) ----
__global__ __launch_bounds__(256) void prep_kernel(
    const float* __restrict__ x, int8_t* __restrict__ xq,
    float* __restrict__ sx, const float* __restrict__ upw,
    int8_t* __restrict__ upq, const float* __restrict__ dnw,
    int8_t* __restrict__ dnq) {
  const int bid = blockIdx.x;
  const int tid = threadIdx.x;
  if (bid < 4096) {
    const int row = bid;
    const float4* xr = (const float4*)(x + (size_t)row * 2048);
    float4 a = xr[tid * 2], b = xr[tid * 2 + 1];
    float m = fmaxf(fmaxf(fmaxf(fabsf(a.x), fabsf(a.y)), fmaxf(fabsf(a.z), fabsf(a.w))),
                    fmaxf(fmaxf(fabsf(b.x), fabsf(b.y)), fmaxf(fabsf(b.z), fabsf(b.w))));
#pragma unroll
    for (int off = 32; off >= 1; off >>= 1) m = fmaxf(m, __shfl_xor(m, off));
    __shared__ float red[4];
    if ((tid & 63) == 0) red[tid >> 6] = m;
    __syncthreads();
    m = fmaxf(fmaxf(red[0], red[1]), fmaxf(red[2], red[3]));
    const float inv = m > 0.f ? 127.f / m : 0.f;
    if (tid == 0) sx[row] = m > 0.f ? m / 127.f : 0.f;
    auto q8 = [&](float v) -> uint32_t {
      float q = rintf(v * inv);
      q = fminf(fmaxf(q, -127.f), 127.f);
      return (uint32_t)(uint8_t)(int8_t)(int)q;
    };
    uint32_t w0 = q8(a.x) | (q8(a.y) << 8) | (q8(a.z) << 16) | (q8(a.w) << 24);
    uint32_t w1 = q8(b.x) | (q8(b.y) << 8) | (q8(b.z) << 16) | (q8(b.w) << 24);
    uint32_t* o = (uint32_t*)(xq + (size_t)row * 2048);
    o[tid * 2] = w0;
    o[tid * 2 + 1] = w1;
  } else {
    const bool is_up = bid < 6144;
    const float* __restrict__ W = is_up ? upw : dnw;
    int8_t* __restrict__ Q = is_up ? upq : dnq;
    const int vb = bid - (is_up ? 4096 : 6144);
    const int n4 = (DH * DM) / 4;
    const int stride = 2048 * 256;
    auto s8 = [](float v) -> uint32_t {
      int s = (v > 0.f) - (v < 0.f);
      return (uint32_t)(uint8_t)(int8_t)s;
    };
    for (int i = vb * 256 + tid; i < n4; i += stride) {
      float4 v = ((const float4*)W)[i];
      ((uint32_t*)Q)[i] = s8(v.x) | (s8(v.y) << 8) | (s8(v.z) << 16) | (s8(v.w) << 24);
    }
  }
}

// ---------------- GEMM1: persistent 4-tile conveyor, swapped-operand --------
// hq = clamp(rint(relu((xq @ upq^T) * ups[col]) / 64), 0, 127) -> i8.
// grid 256. Swapped mfma(bfr, af) -> lane holds row m = ..+lr and 4
// consecutive cols n = ..+lg*4+r -> packed u32 stores (16/thread/epilogue).
__global__ __launch_bounds__(512, 2) void gemm1_i8_kernel(
    const int8_t* __restrict__ A, const int8_t* __restrict__ B,
    int8_t* __restrict__ C, const float* __restrict__ ups,
    int M, int N, int K) {
  constexpr int ABYTES = 256 * 128;     // 32768
  constexpr int BBYTES = 128 * 128;     // 16384
  constexpr int BUFB = ABYTES + BBYTES; // 49152
  constexpr int NG = 64;                // 4 ot x 16 t
  extern __shared__ char smem[];

  const int bid = blockIdx.x;
  const int cpx = gridDim.x >> 3;       // 256 % 8 == 0
  const int swz = (bid & 7) * cpx + (bid >> 3);
  const int bm = swz >> 4;              // 0..15
  const int bnb = (swz & 15) << 2;      // bn base, 4 consecutive columns

  const int tid = threadIdx.x;
  const int lane = tid & 63;
  const int wv = tid >> 6;
  const int wm = wv >> 1, wn = wv & 1;  // 4 x 2 waves, 64x64 each
  const int lr = lane & 15, lg = lane >> 4;

  const int srow = tid >> 3;
  const int scolB = ((tid & 7) ^ (srow & 7)) << 4;   // pre-swizzled src col
  const int8_t* aS = A + (size_t)(bm * 256 + srow) * K + scolB;
  const int8_t* bS0 = B + (size_t)srow * K + scolB;
  const int ldsl = wv * 1024;

  i32x4 acc[4][4] = {};

  auto STAGE = [&](int g, int q) {
    const int ot = g >> 4, t = g & 15;
    char* dA = smem + q * BUFB;
    char* dB = dA + ABYTES;
    const int8_t* a0 = aS + (size_t)t * 128;
    const int8_t* b0 = bS0 + (size_t)((bnb + ot) * 128) * K + (size_t)t * 128;
#pragma unroll
    for (int a = 0; a < 4; ++a)
      GLD16(a0 + (size_t)(a * 64) * K, dA + a * 8192 + ldsl);
#pragma unroll
    for (int b = 0; b < 2; ++b)
      GLD16(b0 + (size_t)(b * 64) * K, dB + b * 8192 + ldsl);
  };

  STAGE(0, 0);
  STAGE(1, 1);
  asm volatile("s_waitcnt vmcnt(6)" ::: "memory");
  __builtin_amdgcn_s_barrier();

  const int xorv = (lr & 7) << 4;
  int cur = 0;
  for (int g = 0; g < NG; ++g) {
    int nx = cur + 2; nx = (nx >= 3) ? nx - 3 : nx;
    if (g + 2 < NG) STAGE(g + 2, nx);

    const char* cA = smem + cur * BUFB;
    const char* cB = cA + ABYTES;
    i32x4 af[2][4], bfr[2][4];
#pragma unroll
    for (int ks = 0; ks < 2; ++ks) {
      int ko = ((ks << 6) + (lg << 4)) ^ xorv;
#pragma unroll
      for (int i = 0; i < 4; ++i)
        af[ks][i] = *(const i32x4*)(cA + ((wm * 64 + i * 16 + lr) << 7) + ko);
#pragma unroll
      for (int j = 0; j < 4; ++j)
        bfr[ks][j] = *(const i32x4*)(cB + ((wn * 64 + j * 16 + lr) << 7) + ko);
    }

    __builtin_amdgcn_s_setprio(1);
#pragma unroll
    for (int ks = 0; ks < 2; ++ks)
#pragma unroll
      for (int i = 0; i < 4; ++i)
#pragma unroll
        for (int j = 0; j < 4; ++j)
          acc[i][j] = __builtin_amdgcn_mfma_i32_16x16x64_i8(
              bfr[ks][j], af[ks][i], acc[i][j], 0, 0, 0);  // SWAPPED
    __builtin_amdgcn_s_setprio(0);

    if (g + 2 < NG) {
      asm volatile("s_waitcnt vmcnt(6)" ::: "memory");
    } else if (g + 1 < NG) {
      asm volatile("s_waitcnt vmcnt(0)" ::: "memory");
    }
    __builtin_amdgcn_s_barrier();
    cur = cur + 1; if (cur == 3) cur = 0;

    // ---- per-ot epilogue: packed u32 stores (transposed C layout) ----
    // lane holds: row m = bm*256 + wm*64 + i*16 + lr;
    //             cols n = bncol + wn*64 + j*16 + lg*4 + {0..3} = acc[i][j][r]
    if ((g & 15) == 15) {
      const int ot = g >> 4;
      const int bncol = (bnb + ot) << 7;
#pragma unroll
      for (int j = 0; j < 4; ++j) {
        const int nbase = bncol + wn * 64 + j * 16 + lg * 4;
        float4 uc4 = *(const float4*)(ups + nbase);
        float u0 = uc4.x * 0.015625f, u1 = uc4.y * 0.015625f;
        float u2 = uc4.z * 0.015625f, u3 = uc4.w * 0.015625f;
#pragma unroll
        for (int i = 0; i < 4; ++i) {
          const int m = bm * 256 + wm * 64 + i * 16 + lr;
          float q0 = fminf(rintf(fmaxf((float)acc[i][j][0] * u0, 0.f)), 127.f);
          float q1 = fminf(rintf(fmaxf((float)acc[i][j][1] * u1, 0.f)), 127.f);
          float q2 = fminf(rintf(fmaxf((float)acc[i][j][2] * u2, 0.f)), 127.f);
          float q3 = fminf(rintf(fmaxf((float)acc[i][j][3] * u3, 0.f)), 127.f);
          uint32_t w = (uint32_t)(uint8_t)(int8_t)(int)q0 |
                       ((uint32_t)(uint8_t)(int8_t)(int)q1 << 8) |
                       ((uint32_t)(uint8_t)(int8_t)(int)q2 << 16) |
                       ((uint32_t)(uint8_t)(int8_t)(int)q3 << 24);
          *(uint32_t*)(C + (size_t)m * N + nbase) = w;
          acc[i][j][0] = 0; acc[i][j][1] = 0; acc[i][j][2] = 0; acc[i][j][3] = 0;
        }
      }
    }
  }
}

// ---------------- GEMM2: 256x128 i8, 3-buffer schedule (r9 verbatim) --------
__global__ __launch_bounds__(512, 2) void gemm2_i8_kernel(
    const int8_t* __restrict__ A, const int8_t* __restrict__ B,
    float* __restrict__ C, const float* __restrict__ sx,
    const float* __restrict__ dns, const float* __restrict__ oscale,
    int M, int N, int K) {
  constexpr int ABYTES = 256 * 128;     // 32768
  constexpr int BBYTES = 128 * 128;     // 16384
  constexpr int BUFB = ABYTES + BBYTES; // 49152
  extern __shared__ char smem[];

  const int nbn = N >> 7;
  const int bid = blockIdx.x;
  const int cpx = gridDim.x >> 3;
  const int swz = (bid & 7) * cpx + (bid >> 3);
  const int bm = swz / nbn, bn = swz % nbn;

  const int tid = threadIdx.x;
  const int lane = tid & 63;
  const int wv = tid >> 6;
  const int wm = wv >> 1, wn = wv & 1;  // 4 x 2 waves, 64x64 each
  const int lr = lane & 15, lg = lane >> 4;

  const int srow = tid >> 3;
  const int scolB = ((tid & 7) ^ (srow & 7)) << 4;
  const int8_t* aS = A + (size_t)(bm * 256 + srow) * K + scolB;
  const int8_t* bS = B + (size_t)(bn * 128 + srow) * K + scolB;
  const int ldsl = wv * 1024;

  i32x4 acc[4][4] = {};
  const int nt = K >> 7;

  auto STAGE = [&](int t, int q) {
    char* dA = smem + q * BUFB;
    char* dB = dA + ABYTES;
    const int8_t* a0 = aS + (size_t)t * 128;
    const int8_t* b0 = bS + (size_t)t * 128;
#pragma unroll
    for (int a = 0; a < 4; ++a)
      GLD16(a0 + (size_t)(a * 64) * K, dA + a * 8192 + ldsl);
#pragma unroll
    for (int b = 0; b < 2; ++b)
      GLD16(b0 + (size_t)(b * 64) * K, dB + b * 8192 + ldsl);
  };

  STAGE(0, 0);
  STAGE(1, 1);
  asm volatile("s_waitcnt vmcnt(6)" ::: "memory");
  __builtin_amdgcn_s_barrier();

  const int xorv = (lr & 7) << 4;
  int cur = 0;
  for (int t = 0; t < nt; ++t) {
    int nx = cur + 2; nx = (nx >= 3) ? nx - 3 : nx;
    if (t + 2 < nt) STAGE(t + 2, nx);

    const char* cA = smem + cur * BUFB;
    const char* cB = cA + ABYTES;
    i32x4 af[2][4], bfr[2][4];
#pragma unroll
    for (int ks = 0; ks < 2; ++ks) {
      int ko = ((ks << 6) + (lg << 4)) ^ xorv;
#pragma unroll
      for (int i = 0; i < 4; ++i)
        af[ks][i] = *(const i32x4*)(cA + ((wm * 64 + i * 16 + lr) << 7) + ko);
#pragma unroll
      for (int j = 0; j < 4; ++j)
        bfr[ks][j] = *(const i32x4*)(cB + ((wn * 64 + j * 16 + lr) << 7) + ko);
    }

    __builtin_amdgcn_s_setprio(1);
#pragma unroll
    for (int ks = 0; ks < 2; ++ks)
#pragma unroll
      for (int i = 0; i < 4; ++i)
#pragma unroll
        for (int j = 0; j < 4; ++j)
          acc[i][j] = __builtin_amdgcn_mfma_i32_16x16x64_i8(
              af[ks][i], bfr[ks][j], acc[i][j], 0, 0, 0);
    __builtin_amdgcn_s_setprio(0);

    if (t + 2 < nt) {
      asm volatile("s_waitcnt vmcnt(6)" ::: "memory");
    } else if (t + 1 < nt) {
      asm volatile("s_waitcnt vmcnt(0)" ::: "memory");
    }
    __builtin_amdgcn_s_barrier();
    cur = cur + 1; if (cur == 3) cur = 0;
  }

  float osc_v = oscale[0] * 64.f;
  float dc[4];
#pragma unroll
  for (int j = 0; j < 4; ++j)
    dc[j] = dns[bn * 128 + wn * 64 + j * 16 + lr] * osc_v;
#pragma unroll
  for (int i = 0; i < 4; ++i) {
    int gr = bm * 256 + wm * 64 + i * 16 + lg * 4;
    float4 shv = *(const float4*)(sx + gr);
#pragma unroll
    for (int j = 0; j < 4; ++j) {
      int gcol = bn * 128 + wn * 64 + j * 16 + lr;
      C[(size_t)(gr + 0) * N + gcol] = (float)acc[i][j][0] * shv.x * dc[j];
      C[(size_t)(gr + 1) * N + gcol] = (float)acc[i][j][1] * shv.y * dc[j];
      C[(size_t)(gr + 2) * N + gcol] = (float)acc[i][j][2] * shv.z * dc[j];
      C[(size_t)(gr + 3) * N + gcol] = (float)acc[i][j][3] * shv.w * dc[j];
    }
  }
}

extern "C" void kernel_launch(void* const* d_in, const int* in_sizes, int n_in,
                              void* d_out, int out_size, void* d_ws,
                              size_t ws_size, hipStream_t stream) {
  const float* x   = (const float*)d_in[0];
  const float* upw = (const float*)d_in[1];
  const float* dnw = (const float*)d_in[2];
  const float* ups = (const float*)d_in[3];
  const float* dns = (const float*)d_in[4];
  const float* osc = (const float*)d_in[5];
  float* out = (float*)d_out;

  char* ws = (char*)d_ws;
  int8_t* xq  = (int8_t*)(ws);              //  8 MB [4096][2048]
  int8_t* upq = (int8_t*)(ws + 8388608);    // 16 MB [8192][2048]
  int8_t* dnq = (int8_t*)(ws + 25165824);   // 16 MB [2048][8192]
  int8_t* hq  = (int8_t*)(ws + 41943040);   // 32 MB [4096][8192]
  float*  sx  = (float*)(ws + 75497472);    // 16 KB [4096]

  prep_kernel<<<8192, 256, 0, stream>>>(x, xq, sx, upw, upq, dnw, dnq);

  const int smem = 147456;  // 3 x 48 KB
  (void)hipFuncSetAttribute(reinterpret_cast<const void*>(gemm1_i8_kernel),
                            hipFuncAttributeMaxDynamicSharedMemorySize, smem);
  (void)hipFuncSetAttribute(reinterpret_cast<const void*>(gemm2_i8_kernel),
                            hipFuncAttributeMaxDynamicSharedMemorySize, smem);

  // GEMM1: persistent conveyor, grid 256 (1 block/CU), 4 output tiles/block.
  gemm1_i8_kernel<<<256, 512, smem, stream>>>(
      xq, upq, hq, ups, M_TOK, DH, DM);
  // GEMM2: out = (hq @ dnq^T) * sx*64 * dns * osc -> f32. grid 256.
  gemm2_i8_kernel<<<(M_TOK / 256) * (DM / 128), 512, smem, stream>>>(
      hq, dnq, out, sx, dns, osc, M_TOK, DM, DH);
}

// Round 15
// 172.325 us; speedup vs baseline: 1.0349x; 1.0349x over previous
//
#include <hip/hip_runtime.h>
#include <stdint.h>

// TriXTile: out = (relu((x @ sign(up_w)^T) * up_scale) @ sign(down_w)^T) * down_scale * out_scale
// Round 15: REVERT to round-10 verbatim (best measured: 172.8 us, replay-stable).
// r11-r14 GEMM1 experiments (GEMM2-clone@nt16, 16-wave, conveyor, packed-store)
// all regressed vs r10's 256x256 2-barrier relaxed kernel (77.7 us).
// Decomposition: prep @ HBM floor, GEMM2 @ LDS floor, GEMM1 @ 6-variant plateau.

#define M_TOK 4096
#define DM 2048
#define DH 8192

typedef __attribute__((ext_vector_type(4))) int i32x4;

#define GLD16(g, l)                                                     \
  __builtin_amdgcn_global_load_lds(                                     \
      (const __attribute__((address_space(1))) void*)(g),               \
      (__attribute__((address_space(3))) void*)(l), 16, 0, 0)

// ---- merged prepass ----
__global__ __launch_bounds__(256) void prep_kernel(
    const float* __restrict__ x, int8_t* __restrict__ xq,
    float* __restrict__ sx, const float* __restrict__ upw,
    int8_t* __restrict__ upq, const float* __restrict__ dnw,
    int8_t* __restrict__ dnq) {
  const int bid = blockIdx.x;
  const int tid = threadIdx.x;
  if (bid < 4096) {
    const int row = bid;
    const float4* xr = (const float4*)(x + (size_t)row * 2048);
    float4 a = xr[tid * 2], b = xr[tid * 2 + 1];
    float m = fmaxf(fmaxf(fmaxf(fabsf(a.x), fabsf(a.y)), fmaxf(fabsf(a.z), fabsf(a.w))),
                    fmaxf(fmaxf(fabsf(b.x), fabsf(b.y)), fmaxf(fabsf(b.z), fabsf(b.w))));
#pragma unroll
    for (int off = 32; off >= 1; off >>= 1) m = fmaxf(m, __shfl_xor(m, off));
    __shared__ float red[4];
    if ((tid & 63) == 0) red[tid >> 6] = m;
    __syncthreads();
    m = fmaxf(fmaxf(red[0], red[1]), fmaxf(red[2], red[3]));
    const float inv = m > 0.f ? 127.f / m : 0.f;
    if (tid == 0) sx[row] = m > 0.f ? m / 127.f : 0.f;
    auto q8 = [&](float v) -> uint32_t {
      float q = rintf(v * inv);
      q = fminf(fmaxf(q, -127.f), 127.f);
      return (uint32_t)(uint8_t)(int8_t)(int)q;
    };
    uint32_t w0 = q8(a.x) | (q8(a.y) << 8) | (q8(a.z) << 16) | (q8(a.w) << 24);
    uint32_t w1 = q8(b.x) | (q8(b.y) << 8) | (q8(b.z) << 16) | (q8(b.w) << 24);
    uint32_t* o = (uint32_t*)(xq + (size_t)row * 2048);
    o[tid * 2] = w0;
    o[tid * 2 + 1] = w1;
  } else {
    const bool is_up = bid < 6144;
    const float* __restrict__ W = is_up ? upw : dnw;
    int8_t* __restrict__ Q = is_up ? upq : dnq;
    const int vb = bid - (is_up ? 4096 : 6144);
    const int n4 = (DH * DM) / 4;
    const int stride = 2048 * 256;
    auto s8 = [](float v) -> uint32_t {
      int s = (v > 0.f) - (v < 0.f);
      return (uint32_t)(uint8_t)(int8_t)s;
    };
    for (int i = vb * 256 + tid; i < n4; i += stride) {
      float4 v = ((const float4*)W)[i];
      ((uint32_t*)Q)[i] = s8(v.x) | (s8(v.y) << 8) | (s8(v.z) << 16) | (s8(v.w) << 24);
    }
  }
}

// ---------------- GEMM1: 256x256 i8, 2-barrier skeleton, relaxed inner ------
// hq[M,N] = clamp(rint(relu((xq @ upq^T) * ups[col]) / 64), 0, 127) -> i8.
// K=2048B, BK=128B, nt=16. 512 thr, 8 waves 2Mx4N, 128x64/wave.
// EARLY {6,7,1,3}->other buf mid-tile; B1; LATE {0,2,4,5}->cur buf; vmcnt(4); B2.
__global__ __launch_bounds__(512, 2) void gemm1_i8_kernel(
    const int8_t* __restrict__ A, const int8_t* __restrict__ B,
    int8_t* __restrict__ C, const float* __restrict__ ups,
    int M, int N, int K) {
  constexpr int TILEB = 256 * 128;      // 32768
  constexpr int BUFB = 2 * TILEB;       // 65536
  extern __shared__ char smem[];

  const int nbn = N >> 8;
  const int bid = blockIdx.x;
  const int cpx = gridDim.x >> 3;
  const int swz = (bid & 7) * cpx + (bid >> 3);
  const int bm = swz / nbn, bn = swz % nbn;

  const int tid = threadIdx.x;
  const int lane = tid & 63;
  const int wv = tid >> 6;
  const int wm = wv >> 2, wn = wv & 3;  // 2 x 4 waves, 128x64 each
  const int lr = lane & 15, lg = lane >> 4;

  const int srow = tid >> 3;
  const int scolB = ((tid & 7) ^ (srow & 7)) << 4;   // pre-swizzled src col
  const int8_t* aS = A + (size_t)(bm * 256 + srow) * K + scolB;
  const int8_t* bS = B + (size_t)(bn * 256 + srow) * K + scolB;
  const int ldsl = wv * 1024;

  auto STAGE = [&](int t, int u) {
    char* dst = smem + (t & 1) * BUFB + u * 8192 + ldsl;
    const int8_t* src = (u < 4) ? aS + (size_t)(u * 64) * K + (size_t)t * 128
                                : bS + (size_t)((u - 4) * 64) * K + (size_t)t * 128;
    GLD16(src, dst);
  };

  const int nt = K >> 7;
  i32x4 acc[8][4] = {};

  // Prologue: tile0 all 8 units + LATE(1); vmcnt(4) retires tile0.
#pragma unroll
  for (int u = 0; u < 8; ++u) STAGE(0, u);
  if (nt > 1) {
    STAGE(1, 0); STAGE(1, 2); STAGE(1, 4); STAGE(1, 5);
    asm volatile("s_waitcnt vmcnt(4)" ::: "memory");
  } else {
    asm volatile("s_waitcnt vmcnt(0)" ::: "memory");
  }
  __builtin_amdgcn_s_barrier();

  const int xorv = (lr & 7) << 4;
  const int k0 = (lg << 4) ^ xorv;
  const int k1 = (64 + (lg << 4)) ^ xorv;
  const int abase = (wm * 128 + lr) * 128;
  const int bbase = TILEB + (wn * 64 + lr) * 128;

  for (int t = 0; t < nt; ++t) {
    const char* bufc = smem + (t & 1) * BUFB;
    const char* bA = bufc + abase;
    const char* bB = bufc + bbase;

    i32x4 b0[4], b1[4];
#pragma unroll
    for (int fc = 0; fc < 4; ++fc) {
      b0[fc] = *(const i32x4*)(bB + fc * 2048 + k0);
      b1[fc] = *(const i32x4*)(bB + fc * 2048 + k1);
    }
    // EARLY stages: tile t+1 units {6,7,1,3} -> other buffer.
    if (t + 1 < nt) { STAGE(t + 1, 6); STAGE(t + 1, 7);
                      STAGE(t + 1, 1); STAGE(t + 1, 3); }

#pragma unroll
    for (int qd = 0; qd < 4; ++qd) {
      i32x4 a0 = *(const i32x4*)(bA + (2 * qd) * 2048 + k0);
      i32x4 a1 = *(const i32x4*)(bA + (2 * qd) * 2048 + k1);
      i32x4 a2 = *(const i32x4*)(bA + (2 * qd + 1) * 2048 + k0);
      i32x4 a3 = *(const i32x4*)(bA + (2 * qd + 1) * 2048 + k1);
      __builtin_amdgcn_s_setprio(1);
#pragma unroll
      for (int fc = 0; fc < 4; ++fc)
        acc[2 * qd][fc] = __builtin_amdgcn_mfma_i32_16x16x64_i8(
            a0, b0[fc], acc[2 * qd][fc], 0, 0, 0);
#pragma unroll
      for (int fc = 0; fc < 4; ++fc)
        acc[2 * qd + 1][fc] = __builtin_amdgcn_mfma_i32_16x16x64_i8(
            a2, b0[fc], acc[2 * qd + 1][fc], 0, 0, 0);
#pragma unroll
      for (int fc = 0; fc < 4; ++fc)
        acc[2 * qd][fc] = __builtin_amdgcn_mfma_i32_16x16x64_i8(
            a1, b1[fc], acc[2 * qd][fc], 0, 0, 0);
#pragma unroll
      for (int fc = 0; fc < 4; ++fc)
        acc[2 * qd + 1][fc] = __builtin_amdgcn_mfma_i32_16x16x64_i8(
            a3, b1[fc], acc[2 * qd + 1][fc], 0, 0, 0);
      __builtin_amdgcn_s_setprio(0);
    }

    // Pin ds_read issue above B1, then B1: all waves done reading buffer.
    __builtin_amdgcn_sched_barrier(0);
    __builtin_amdgcn_s_barrier();
    // LATE stages: tile t+2 units {0,2,4,5} -> current buffer (now dead).
    if (t + 2 < nt) { STAGE(t + 2, 0); STAGE(t + 2, 2);
                      STAGE(t + 2, 4); STAGE(t + 2, 5); }
    // Ledger: L(t+1)[4] + E(t+1)[4] + L(t+2)[4] = 12; retire tile t+1.
    if (t + 2 < nt) {
      asm volatile("s_waitcnt vmcnt(4)" ::: "memory");
    } else {
      asm volatile("s_waitcnt vmcnt(0)" ::: "memory");
    }
    __builtin_amdgcn_s_barrier();   // B2: tile t+1 published
    __builtin_amdgcn_sched_barrier(0);
  }

  // Epilogue: hq = clamp(rint(relu(acc * ups[col]) / 64), 0, 127) -> i8
  float uc[4];
#pragma unroll
  for (int fc = 0; fc < 4; ++fc)
    uc[fc] = ups[bn * 256 + wn * 64 + fc * 16 + lr] * 0.015625f;
#pragma unroll
  for (int fr = 0; fr < 8; ++fr) {
    int gr = bm * 256 + wm * 128 + fr * 16 + lg * 4;
#pragma unroll
    for (int fc = 0; fc < 4; ++fc) {
      int gcol = bn * 256 + wn * 64 + fc * 16 + lr;
#pragma unroll
      for (int r = 0; r < 4; ++r) {
        float q = rintf(fmaxf((float)acc[fr][fc][r] * uc[fc], 0.f));
        q = fminf(q, 127.f);
        C[(size_t)(gr + r) * N + gcol] = (int8_t)(int)q;
      }
    }
  }
}

// ---------------- GEMM2: 256x128 i8, 3-buffer schedule ----------------------
__global__ __launch_bounds__(512, 2) void gemm2_i8_kernel(
    const int8_t* __restrict__ A, const int8_t* __restrict__ B,
    float* __restrict__ C, const float* __restrict__ sx,
    const float* __restrict__ dns, const float* __restrict__ oscale,
    int M, int N, int K) {
  constexpr int ABYTES = 256 * 128;     // 32768
  constexpr int BBYTES = 128 * 128;     // 16384
  constexpr int BUFB = ABYTES + BBYTES; // 49152
  extern __shared__ char smem[];

  const int nbn = N >> 7;
  const int bid = blockIdx.x;
  const int cpx = gridDim.x >> 3;
  const int swz = (bid & 7) * cpx + (bid >> 3);
  const int bm = swz / nbn, bn = swz % nbn;

  const int tid = threadIdx.x;
  const int lane = tid & 63;
  const int wv = tid >> 6;
  const int wm = wv >> 1, wn = wv & 1;  // 4 x 2 waves, 64x64 each
  const int lr = lane & 15, lg = lane >> 4;

  const int srow = tid >> 3;
  const int scolB = ((tid & 7) ^ (srow & 7)) << 4;
  const int8_t* aS = A + (size_t)(bm * 256 + srow) * K + scolB;
  const int8_t* bS = B + (size_t)(bn * 128 + srow) * K + scolB;
  const int ldsl = wv * 1024;

  i32x4 acc[4][4] = {};
  const int nt = K >> 7;

  auto STAGE = [&](int t, int q) {
    char* dA = smem + q * BUFB;
    char* dB = dA + ABYTES;
    const int8_t* a0 = aS + (size_t)t * 128;
    const int8_t* b0 = bS + (size_t)t * 128;
#pragma unroll
    for (int a = 0; a < 4; ++a)
      GLD16(a0 + (size_t)(a * 64) * K, dA + a * 8192 + ldsl);
#pragma unroll
    for (int b = 0; b < 2; ++b)
      GLD16(b0 + (size_t)(b * 64) * K, dB + b * 8192 + ldsl);
  };

  STAGE(0, 0);
  STAGE(1, 1);
  asm volatile("s_waitcnt vmcnt(6)" ::: "memory");
  __builtin_amdgcn_s_barrier();

  const int xorv = (lr & 7) << 4;
  int cur = 0;
  for (int t = 0; t < nt; ++t) {
    int nx = cur + 2; nx = (nx >= 3) ? nx - 3 : nx;
    if (t + 2 < nt) STAGE(t + 2, nx);

    const char* cA = smem + cur * BUFB;
    const char* cB = cA + ABYTES;
    i32x4 af[2][4], bfr[2][4];
#pragma unroll
    for (int ks = 0; ks < 2; ++ks) {
      int ko = ((ks << 6) + (lg << 4)) ^ xorv;
#pragma unroll
      for (int i = 0; i < 4; ++i)
        af[ks][i] = *(const i32x4*)(cA + ((wm * 64 + i * 16 + lr) << 7) + ko);
#pragma unroll
      for (int j = 0; j < 4; ++j)
        bfr[ks][j] = *(const i32x4*)(cB + ((wn * 64 + j * 16 + lr) << 7) + ko);
    }

    __builtin_amdgcn_s_setprio(1);
#pragma unroll
    for (int ks = 0; ks < 2; ++ks)
#pragma unroll
      for (int i = 0; i < 4; ++i)
#pragma unroll
        for (int j = 0; j < 4; ++j)
          acc[i][j] = __builtin_amdgcn_mfma_i32_16x16x64_i8(
              af[ks][i], bfr[ks][j], acc[i][j], 0, 0, 0);
    __builtin_amdgcn_s_setprio(0);

    if (t + 2 < nt) {
      asm volatile("s_waitcnt vmcnt(6)" ::: "memory");
    } else if (t + 1 < nt) {
      asm volatile("s_waitcnt vmcnt(0)" ::: "memory");
    }
    __builtin_amdgcn_s_barrier();
    cur = cur + 1; if (cur == 3) cur = 0;
  }

  float osc_v = oscale[0] * 64.f;
  float dc[4];
#pragma unroll
  for (int j = 0; j < 4; ++j)
    dc[j] = dns[bn * 128 + wn * 64 + j * 16 + lr] * osc_v;
#pragma unroll
  for (int i = 0; i < 4; ++i) {
    int gr = bm * 256 + wm * 64 + i * 16 + lg * 4;
    float4 shv = *(const float4*)(sx + gr);
#pragma unroll
    for (int j = 0; j < 4; ++j) {
      int gcol = bn * 128 + wn * 64 + j * 16 + lr;
      C[(size_t)(gr + 0) * N + gcol] = (float)acc[i][j][0] * shv.x * dc[j];
      C[(size_t)(gr + 1) * N + gcol] = (float)acc[i][j][1] * shv.y * dc[j];
      C[(size_t)(gr + 2) * N + gcol] = (float)acc[i][j][2] * shv.z * dc[j];
      C[(size_t)(gr + 3) * N + gcol] = (float)acc[i][j][3] * shv.w * dc[j];
    }
  }
}

extern "C" void kernel_launch(void* const* d_in, const int* in_sizes, int n_in,
                              void* d_out, int out_size, void* d_ws,
                              size_t ws_size, hipStream_t stream) {
  const float* x   = (const float*)d_in[0];
  const float* upw = (const float*)d_in[1];
  const float* dnw = (const float*)d_in[2];
  const float* ups = (const float*)d_in[3];
  const float* dns = (const float*)d_in[4];
  const float* osc = (const float*)d_in[5];
  float* out = (float*)d_out;

  char* ws = (char*)d_ws;
  int8_t* xq  = (int8_t*)(ws);              //  8 MB [4096][2048]
  int8_t* upq = (int8_t*)(ws + 8388608);    // 16 MB [8192][2048]
  int8_t* dnq = (int8_t*)(ws + 25165824);   // 16 MB [2048][8192]
  int8_t* hq  = (int8_t*)(ws + 41943040);   // 32 MB [4096][8192]
  float*  sx  = (float*)(ws + 75497472);    // 16 KB [4096]

  prep_kernel<<<8192, 256, 0, stream>>>(x, xq, sx, upw, upq, dnw, dnq);

  const int smem1 = 131072;  // 2 x 64 KB
  const int smem2 = 147456;  // 3 x 48 KB
  (void)hipFuncSetAttribute(reinterpret_cast<const void*>(gemm1_i8_kernel),
                            hipFuncAttributeMaxDynamicSharedMemorySize, smem1);
  (void)hipFuncSetAttribute(reinterpret_cast<const void*>(gemm2_i8_kernel),
                            hipFuncAttributeMaxDynamicSharedMemorySize, smem2);

  // GEMM1: hq = quant64(relu((xq @ upq^T) * ups)) -> i8. grid 16*32 = 512.
  gemm1_i8_kernel<<<(M_TOK / 256) * (DH / 256), 512, smem1, stream>>>(
      xq, upq, hq, ups, M_TOK, DH, DM);
  // GEMM2: out = (hq @ dnq^T) * sx*64 * dns * osc -> f32. grid 16*16 = 256.
  gemm2_i8_kernel<<<(M_TOK / 256) * (DM / 128), 512, smem2, stream>>>(
      hq, dnq, out, sx, dns, osc, M_TOK, DM, DH);
}